// Round 6
// baseline (677.223 us; speedup 1.0000x reference)
//
#include <hip/hip_runtime.h>
#include <math.h>

#define B_ 64
#define T_ 4096
#define D_ 256
#define U_ 64
#define CH 64            // rows per chunk (4 waves x 16 rows)
#define NCHUNK 8         // chunks per block
#define BPB 8            // blocks per batch: BPB*NCHUNK*CH == T_

typedef float f32x4 __attribute__((ext_vector_type(4)));
typedef short bf16x8 __attribute__((ext_vector_type(8)));

__device__ __forceinline__ unsigned short f2bf_rne(float f) {
    unsigned u = __float_as_uint(f);
    unsigned r = u + 0x7fffu + ((u >> 16) & 1u);
    return (unsigned short)(r >> 16);
}
__device__ __forceinline__ float bfbits2f(unsigned short s) {
    return __uint_as_float(((unsigned)s) << 16);
}

// Pack W [D,U] fp32 into MFMA B-fragment order, split hi/lo bf16.
// Fragment (ks,nt,lane,j): value = W[k = ks*32 + (lane>>4)*8 + j][n = nt*16 + (lane&15)]
__global__ __launch_bounds__(256) void wprep_kernel(
    const float* __restrict__ W, unsigned short* __restrict__ whi,
    unsigned short* __restrict__ wlo)
{
    int fi = blockIdx.x * 256 + threadIdx.x;   // 0..16383, grid=64
    int j    = fi & 7;
    int lane = (fi >> 3) & 63;
    int tile = fi >> 9;            // 0..31
    int nt = tile & 3, ks = tile >> 2;
    int k = ks * 32 + (lane >> 4) * 8 + j;
    int n = nt * 16 + (lane & 15);
    float w = W[k * U_ + n];
    unsigned short hi = f2bf_rne(w);
    unsigned short lo = f2bf_rne(w - bfbits2f(hi));
    whi[fi] = hi;
    wlo[fi] = lo;
}

// Load one chunk's x (16 float4 per thread) into register buffer xb[16].
#define LOAD_CHUNK(c, xb)                                              \
    do {                                                               \
        const float* xp_ = xbase + (size_t)(c) * CH * D_;              \
        _Pragma("unroll")                                              \
        for (int ks_ = 0; ks_ < 8; ++ks_) {                            \
            xb[2 * ks_]     = *(const float4*)(xp_ + ks_ * 32);        \
            xb[2 * ks_ + 1] = *(const float4*)(xp_ + ks_ * 32 + 4);    \
        }                                                              \
    } while (0)

// Compute one chunk from xb: split-bf16 MFMA -> e = exp(tanh(.)@u) -> wts;
// phase-2 partial P[d] += e * x (fp32, from registers).
#define COMPUTE_CHUNK(c, xb)                                                        \
    do {                                                                            \
        f32x4 acc[4];                                                               \
        _Pragma("unroll")                                                           \
        for (int nt_ = 0; nt_ < 4; ++nt_) acc[nt_] = (f32x4){0.f, 0.f, 0.f, 0.f};   \
        _Pragma("unroll")                                                           \
        for (int ks_ = 0; ks_ < 8; ++ks_) {                                         \
            float4 va_ = xb[2 * ks_], vb_ = xb[2 * ks_ + 1];                        \
            float f_[8] = {va_.x, va_.y, va_.z, va_.w, vb_.x, vb_.y, vb_.z, vb_.w}; \
            union { bf16x8 v; unsigned short s[8]; } hi_, lo_;                      \
            _Pragma("unroll")                                                       \
            for (int j_ = 0; j_ < 8; ++j_) {                                        \
                unsigned short a_ = f2bf_rne(f_[j_]);                               \
                hi_.s[j_] = a_;                                                     \
                lo_.s[j_] = f2bf_rne(f_[j_] - bfbits2f(a_));                        \
            }                                                                       \
            _Pragma("unroll")                                                       \
            for (int nt_ = 0; nt_ < 4; ++nt_) {                                     \
                bf16x8 bh_ = BhV[(ks_ * 4 + nt_) * 64 + lane];                      \
                bf16x8 bl_ = BlV[(ks_ * 4 + nt_) * 64 + lane];                      \
                acc[nt_] = __builtin_amdgcn_mfma_f32_16x16x32_bf16(hi_.v, bh_, acc[nt_], 0, 0, 0); \
                acc[nt_] = __builtin_amdgcn_mfma_f32_16x16x32_bf16(hi_.v, bl_, acc[nt_], 0, 0, 0); \
                acc[nt_] = __builtin_amdgcn_mfma_f32_16x16x32_bf16(lo_.v, bh_, acc[nt_], 0, 0, 0); \
            }                                                                       \
        }                                                                           \
        float p0_ = 0.f, p1_ = 0.f, p2_ = 0.f, p3_ = 0.f;                           \
        _Pragma("unroll")                                                           \
        for (int nt_ = 0; nt_ < 4; ++nt_) {                                         \
            int col_ = nt_ * 16 + r;                                                \
            float bv_ = bias[col_], uv_ = uvec[col_];                               \
            float s0_ = acc[nt_][0] + bv_, s1_ = acc[nt_][1] + bv_,                 \
                  s2_ = acc[nt_][2] + bv_, s3_ = acc[nt_][3] + bv_;                 \
            p0_ = fmaf(1.f - 2.f / (__expf(2.f * s0_) + 1.f), uv_, p0_);            \
            p1_ = fmaf(1.f - 2.f / (__expf(2.f * s1_) + 1.f), uv_, p1_);            \
            p2_ = fmaf(1.f - 2.f / (__expf(2.f * s2_) + 1.f), uv_, p2_);            \
            p3_ = fmaf(1.f - 2.f / (__expf(2.f * s3_) + 1.f), uv_, p3_);            \
        }                                                                           \
        _Pragma("unroll")                                                           \
        for (int off_ = 1; off_ < 16; off_ <<= 1) {                                 \
            p0_ += __shfl_xor(p0_, off_, 64);                                       \
            p1_ += __shfl_xor(p1_, off_, 64);                                       \
            p2_ += __shfl_xor(p2_, off_, 64);                                       \
            p3_ += __shfl_xor(p3_, off_, 64);                                       \
        }                                                                           \
        float e0_ = __expf(p0_), e1_ = __expf(p1_),                                 \
              e2_ = __expf(p2_), e3_ = __expf(p3_);                                 \
        if (r == 0) {                                                               \
            float4 o_ = {e0_, e1_, e2_, e3_};                                       \
            *(float4*)(wbase + (c) * CH + wid * 16 + q * 4) = o_;                   \
        }                                                                           \
        zacc += (e0_ + e1_) + (e2_ + e3_);                                          \
        int src_ = (r >> 2) * 16;                                                   \
        float ea_ = __shfl(e0_, src_, 64), eb_ = __shfl(e1_, src_, 64),             \
              ec_ = __shfl(e2_, src_, 64), ed_ = __shfl(e3_, src_, 64);             \
        float er_ = (r & 2) ? ((r & 1) ? ed_ : ec_) : ((r & 1) ? eb_ : ea_);        \
        _Pragma("unroll")                                                           \
        for (int ks_ = 0; ks_ < 8; ++ks_) {                                         \
            float4 va_ = xb[2 * ks_], vb_ = xb[2 * ks_ + 1];                        \
            P[ks_ * 8 + 0] = fmaf(er_, va_.x, P[ks_ * 8 + 0]);                      \
            P[ks_ * 8 + 1] = fmaf(er_, va_.y, P[ks_ * 8 + 1]);                      \
            P[ks_ * 8 + 2] = fmaf(er_, va_.z, P[ks_ * 8 + 2]);                      \
            P[ks_ * 8 + 3] = fmaf(er_, va_.w, P[ks_ * 8 + 3]);                      \
            P[ks_ * 8 + 4] = fmaf(er_, vb_.x, P[ks_ * 8 + 4]);                      \
            P[ks_ * 8 + 5] = fmaf(er_, vb_.y, P[ks_ * 8 + 5]);                      \
            P[ks_ * 8 + 6] = fmaf(er_, vb_.z, P[ks_ * 8 + 6]);                      \
            P[ks_ * 8 + 7] = fmaf(er_, vb_.w, P[ks_ * 8 + 7]);                      \
        }                                                                           \
    } while (0)

// Fused main: grid = B_*BPB blocks (fully resident at 2/CU). Each block:
// stage W-frags in LDS once; loop 8 chunks of 64 rows with double-buffered
// register prefetch of x; per chunk compute e (split-bf16 MFMA) and fp32
// context partials in registers; one reduction + atomic at the end.
__global__ __launch_bounds__(256, 2) void fused_main(
    const float* __restrict__ x, const unsigned short* __restrict__ whi,
    const unsigned short* __restrict__ wlo, const float* __restrict__ bias,
    const float* __restrict__ uvec, float* __restrict__ wts,
    float* __restrict__ Zp, float* __restrict__ accZ)
{
    __shared__ unsigned short Bh[16384];   // 32 KB
    __shared__ unsigned short Bl[16384];   // 32 KB
    __shared__ float pred[16 * 64];        // 4 KB
    __shared__ float zred[4];

    int tid = threadIdx.x;
    {
        const uint4* sh = (const uint4*)whi;
        const uint4* sl = (const uint4*)wlo;
        uint4* dh = (uint4*)Bh;
        uint4* dl = (uint4*)Bl;
#pragma unroll
        for (int i = 0; i < 8; ++i) {
            dh[tid + i * 256] = sh[tid + i * 256];
            dl[tid + i * 256] = sl[tid + i * 256];
        }
    }
    __syncthreads();

    int lane = tid & 63, wid = tid >> 6;
    int q = lane >> 4, r = lane & 15;
    int b = blockIdx.x / BPB;
    int pb = blockIdx.x % BPB;
    size_t row00 = (size_t)b * T_ + (size_t)pb * (CH * NCHUNK);
    const float* xbase = x + (row00 + wid * 16 + r) * D_ + q * 8;
    float* wbase = wts + row00;

    const bf16x8* BhV = (const bf16x8*)Bh;
    const bf16x8* BlV = (const bf16x8*)Bl;

    float P[64];
#pragma unroll
    for (int i = 0; i < 64; ++i) P[i] = 0.f;
    float zacc = 0.f;

    float4 xb0[16], xb1[16];

    LOAD_CHUNK(0, xb0);
    for (int c = 0; c < NCHUNK; c += 2) {
        LOAD_CHUNK(c + 1, xb1);
        COMPUTE_CHUNK(c, xb0);
        if (c + 2 < NCHUNK) LOAD_CHUNK(c + 2, xb0);
        COMPUTE_CHUNK(c + 1, xb1);
    }

    // Reduce P over the 16 r-lanes (d-set identical within a q-group).
#pragma unroll
    for (int i = 0; i < 64; ++i) {
        P[i] += __shfl_xor(P[i], 1, 64);
        P[i] += __shfl_xor(P[i], 2, 64);
        P[i] += __shfl_xor(P[i], 4, 64);
        P[i] += __shfl_xor(P[i], 8, 64);
    }
    if (r == 0) {
        float* pd = &pred[(wid * 4 + q) * 64];
#pragma unroll
        for (int i = 0; i < 16; ++i)
            *(float4*)(pd + i * 4) =
                (float4){P[4 * i], P[4 * i + 1], P[4 * i + 2], P[4 * i + 3]};
    }
    zacc += __shfl_xor(zacc, 16, 64);
    zacc += __shfl_xor(zacc, 32, 64);
    if (lane == 0) zred[wid] = zacc;
    __syncthreads();
    if (tid == 0) Zp[blockIdx.x] = (zred[0] + zred[1]) + (zred[2] + zred[3]);

    // Cross-wave sum: d = ks*32 + q*8 + j.
    int d = tid;
    int ksd = d >> 5, qd = (d >> 3) & 3, jd = d & 7;
    int idx = ksd * 8 + jd;
    float s = (pred[(0 * 4 + qd) * 64 + idx] + pred[(1 * 4 + qd) * 64 + idx]) +
              (pred[(2 * 4 + qd) * 64 + idx] + pred[(3 * 4 + qd) * 64 + idx]);
    atomicAdd(&accZ[b * D_ + d], s);
}

// Finalize: Z_b = sum of BPB partials; ctx = P/Z; wts *= 1/Z (in place).
__global__ __launch_bounds__(256) void finalize_kernel(
    float* __restrict__ wts, const float* __restrict__ Zp,
    const float* __restrict__ accZ, float* __restrict__ ctx)
{
    int b = blockIdx.x;
    int tid = threadIdx.x;
    float Z = 0.f;
#pragma unroll
    for (int i = 0; i < BPB; ++i) Z += Zp[b * BPB + i];   // uniform s_loads
    float invZ = 1.f / Z;

    ctx[b * D_ + tid] = accZ[b * D_ + tid] * invZ;

    float4* wp = (float4*)(wts + (size_t)b * T_);
#pragma unroll
    for (int i = 0; i < T_ / 4 / 256; ++i) {
        float4 v = wp[tid + i * 256];
        v.x *= invZ; v.y *= invZ; v.z *= invZ; v.w *= invZ;
        wp[tid + i * 256] = v;
    }
}

extern "C" void kernel_launch(void* const* d_in, const int* in_sizes, int n_in,
                              void* d_out, int out_size, void* d_ws, size_t ws_size,
                              hipStream_t stream) {
    const float* x    = (const float*)d_in[0];   // [B,T,D]
    const float* W    = (const float*)d_in[1];   // [D,U]
    const float* bias = (const float*)d_in[2];   // [U]
    const float* uvec = (const float*)d_in[3];   // [U,1]

    float* out = (float*)d_out;
    float* ctx = out;            // context: B*D floats
    float* wts = out + B_ * D_;  // attention weights: B*T floats (e between kernels)

    unsigned short* whi = (unsigned short*)d_ws;     // 32 KB
    unsigned short* wlo = whi + D_ * U_;             // 32 KB
    float* Zp   = (float*)(wlo + D_ * U_);           // B_*BPB partial Z
    float* accZ = Zp + B_ * BPB;                     // B*D unnormalized context

    hipMemsetAsync(accZ, 0, B_ * D_ * sizeof(float), stream);

    wprep_kernel<<<D_ * U_ / 256, 256, 0, stream>>>(W, whi, wlo);
    fused_main<<<B_ * BPB, 256, 0, stream>>>(x, whi, wlo, bias, uvec, wts, Zp, accZ);
    finalize_kernel<<<B_, 256, 0, stream>>>(wts, Zp, accZ, ctx);
}

// Round 7
// 454.457 us; speedup vs baseline: 1.4902x; 1.4902x over previous
//
#include <hip/hip_runtime.h>
#include <math.h>

#define B_ 64
#define T_ 4096
#define D_ 256
#define U_ 64
#define BPB 8            // blocks per batch
#define RPB (T_ / BPB)   // rows per block = 512
#define NCH (RPB / 64)   // 8 chunks of 64 rows (4 waves x 16)

typedef float f32x4 __attribute__((ext_vector_type(4)));
typedef short bf16x8 __attribute__((ext_vector_type(8)));

__device__ __forceinline__ unsigned short f2bf_rne(float f) {
    unsigned u = __float_as_uint(f);
    unsigned r = u + 0x7fffu + ((u >> 16) & 1u);
    return (unsigned short)(r >> 16);
}
__device__ __forceinline__ float bfbits2f(unsigned short s) {
    return __uint_as_float(((unsigned)s) << 16);
}

// Pack W [D,U] fp32 into MFMA B-fragment order, split hi/lo bf16.
// Fragment (ks,nt,lane,j): value = W[k = ks*32 + (lane>>4)*8 + j][n = nt*16 + (lane&15)]
__global__ __launch_bounds__(256) void wprep_kernel(
    const float* __restrict__ W, unsigned short* __restrict__ whi,
    unsigned short* __restrict__ wlo)
{
    int fi = blockIdx.x * 256 + threadIdx.x;   // 0..16383, grid=64
    int j    = fi & 7;
    int lane = (fi >> 3) & 63;
    int tile = fi >> 9;            // 0..31
    int nt = tile & 3, ks = tile >> 2;
    int k = ks * 32 + (lane >> 4) * 8 + j;
    int n = nt * 16 + (lane & 15);
    float w = W[k * U_ + n];
    unsigned short hi = f2bf_rne(w);
    unsigned short lo = f2bf_rne(w - bfbits2f(hi));
    whi[fi] = hi;
    wlo[fi] = lo;
}

// Fused main. Grid = 512 blocks (2/CU resident), each owns 512 rows.
// Loop 1 (8 chunks x 64 rows): x global->reg (only vmcnt users), B-frags from
// LDS (lgkmcnt), split-bf16 MFMA, e=exp(tanh(.)@u) -> esh + wts global.
// One barrier. Loop 2: thread=column, P=sum_rows e*x from L2/L3, partials->Pp.
__global__ __launch_bounds__(256, 2) void fused_main(
    const float* __restrict__ x, const unsigned short* __restrict__ whi,
    const unsigned short* __restrict__ wlo, const float* __restrict__ bias,
    const float* __restrict__ uvec, float* __restrict__ wts,
    float* __restrict__ Zp, float* __restrict__ Pp)
{
    __shared__ unsigned short Bh[16384];   // 32 KB
    __shared__ unsigned short Bl[16384];   // 32 KB
    __shared__ float esh[RPB];             // 2 KB
    __shared__ float zred[4];

    int tid = threadIdx.x;
    {
        const uint4* sh = (const uint4*)whi;
        const uint4* sl = (const uint4*)wlo;
        uint4* dh = (uint4*)Bh;
        uint4* dl = (uint4*)Bl;
#pragma unroll
        for (int i = 0; i < 8; ++i) {
            dh[tid + i * 256] = sh[tid + i * 256];
            dl[tid + i * 256] = sl[tid + i * 256];
        }
    }
    __syncthreads();

    int lane = tid & 63, wid = tid >> 6;
    int q = lane >> 4, r = lane & 15;
    int b = blockIdx.x / BPB;
    int pb = blockIdx.x % BPB;
    size_t row00 = (size_t)b * T_ + (size_t)pb * RPB;
    const float* xlane = x + (row00 + wid * 16 + r) * D_ + q * 8;
    float* wbase = wts + row00;

    const bf16x8* BhV = (const bf16x8*)Bh;
    const bf16x8* BlV = (const bf16x8*)Bl;

    float zacc = 0.f;

#pragma unroll 1
    for (int c = 0; c < NCH; ++c) {
        const float* xp = xlane + (size_t)c * 64 * D_;
        // Batch all 16 x loads (independent; the only vmcnt users in this loop)
        float4 xb[16];
#pragma unroll
        for (int ks = 0; ks < 8; ++ks) {
            xb[2 * ks]     = *(const float4*)(xp + ks * 32);
            xb[2 * ks + 1] = *(const float4*)(xp + ks * 32 + 4);
        }

        f32x4 acc[4];
#pragma unroll
        for (int nt = 0; nt < 4; ++nt) acc[nt] = (f32x4){0.f, 0.f, 0.f, 0.f};

#pragma unroll
        for (int ks = 0; ks < 8; ++ks) {
            float4 va = xb[2 * ks], vb = xb[2 * ks + 1];
            float f[8] = {va.x, va.y, va.z, va.w, vb.x, vb.y, vb.z, vb.w};
            union { bf16x8 v; unsigned short s[8]; } hi_, lo_;
#pragma unroll
            for (int j = 0; j < 8; ++j) {
                unsigned short a = f2bf_rne(f[j]);
                hi_.s[j] = a;
                lo_.s[j] = f2bf_rne(f[j] - bfbits2f(a));
            }
#pragma unroll
            for (int nt = 0; nt < 4; ++nt) {
                bf16x8 bh = BhV[(ks * 4 + nt) * 64 + lane];
                bf16x8 bl = BlV[(ks * 4 + nt) * 64 + lane];
                acc[nt] = __builtin_amdgcn_mfma_f32_16x16x32_bf16(hi_.v, bh, acc[nt], 0, 0, 0);
                acc[nt] = __builtin_amdgcn_mfma_f32_16x16x32_bf16(hi_.v, bl, acc[nt], 0, 0, 0);
                acc[nt] = __builtin_amdgcn_mfma_f32_16x16x32_bf16(lo_.v, bh, acc[nt], 0, 0, 0);
            }
        }

        // Epilogue: p = tanh(acc+bias)@u reduced over 16 col-lanes;
        // e -> esh + wts. C/D: row=q*4+reg, col=nt*16+r.
        float p0 = 0.f, p1 = 0.f, p2 = 0.f, p3 = 0.f;
#pragma unroll
        for (int nt = 0; nt < 4; ++nt) {
            int col = nt * 16 + r;
            float bv = bias[col], uv = uvec[col];
            float s0 = acc[nt][0] + bv, s1 = acc[nt][1] + bv,
                  s2 = acc[nt][2] + bv, s3 = acc[nt][3] + bv;
            p0 = fmaf(1.f - 2.f / (__expf(2.f * s0) + 1.f), uv, p0);
            p1 = fmaf(1.f - 2.f / (__expf(2.f * s1) + 1.f), uv, p1);
            p2 = fmaf(1.f - 2.f / (__expf(2.f * s2) + 1.f), uv, p2);
            p3 = fmaf(1.f - 2.f / (__expf(2.f * s3) + 1.f), uv, p3);
        }
#pragma unroll
        for (int off = 1; off < 16; off <<= 1) {
            p0 += __shfl_xor(p0, off, 64);
            p1 += __shfl_xor(p1, off, 64);
            p2 += __shfl_xor(p2, off, 64);
            p3 += __shfl_xor(p3, off, 64);
        }
        float e0 = __expf(p0), e1 = __expf(p1), e2 = __expf(p2), e3 = __expf(p3);
        if (r == 0) {
            float4 o = {e0, e1, e2, e3};
            int lr = c * 64 + wid * 16 + q * 4;
            *(float4*)(wbase + lr) = o;
            *(float4*)(&esh[lr]) = o;
        }
        zacc += (e0 + e1) + (e2 + e3);
    }

    // zacc: identical across r-lanes; sum over q (lane bits 4,5) and waves.
    zacc += __shfl_xor(zacc, 16, 64);
    zacc += __shfl_xor(zacc, 32, 64);
    if (lane == 0) zred[wid] = zacc;
    __syncthreads();
    if (tid == 0) Zp[blockIdx.x] = (zred[0] + zred[1]) + (zred[2] + zred[3]);

    // Loop 2: column-sum from L2/L3-warm x. Thread tid owns column tid.
    const float* xc = x + row00 * D_ + tid;
    float P0 = 0.f, P1 = 0.f, P2 = 0.f, P3 = 0.f;
#pragma unroll 2
    for (int row = 0; row < RPB; row += 8) {
        float e0 = esh[row + 0], e1 = esh[row + 1], e2 = esh[row + 2], e3 = esh[row + 3];
        float e4 = esh[row + 4], e5 = esh[row + 5], e6 = esh[row + 6], e7 = esh[row + 7];
        float x0 = xc[(size_t)(row + 0) * D_];
        float x1 = xc[(size_t)(row + 1) * D_];
        float x2 = xc[(size_t)(row + 2) * D_];
        float x3 = xc[(size_t)(row + 3) * D_];
        float x4 = xc[(size_t)(row + 4) * D_];
        float x5 = xc[(size_t)(row + 5) * D_];
        float x6 = xc[(size_t)(row + 6) * D_];
        float x7 = xc[(size_t)(row + 7) * D_];
        P0 = fmaf(e0, x0, P0); P1 = fmaf(e1, x1, P1);
        P2 = fmaf(e2, x2, P2); P3 = fmaf(e3, x3, P3);
        P0 = fmaf(e4, x4, P0); P1 = fmaf(e5, x5, P1);
        P2 = fmaf(e6, x6, P2); P3 = fmaf(e7, x7, P3);
    }
    Pp[(size_t)blockIdx.x * D_ + tid] = (P0 + P1) + (P2 + P3);
}

// Finalize: Z_b = sum of BPB partials; ctx = sum(Pp)/Z; wts *= 1/Z.
__global__ __launch_bounds__(256) void finalize_kernel(
    float* __restrict__ wts, const float* __restrict__ Zp,
    const float* __restrict__ Pp, float* __restrict__ ctx)
{
    int b = blockIdx.x;
    int tid = threadIdx.x;
    float Z = 0.f;
#pragma unroll
    for (int i = 0; i < BPB; ++i) Z += Zp[b * BPB + i];   // uniform s_loads
    float invZ = 1.f / Z;

    float s = 0.f;
#pragma unroll
    for (int i = 0; i < BPB; ++i) s += Pp[(size_t)(b * BPB + i) * D_ + tid];
    ctx[b * D_ + tid] = s * invZ;

    float4* wp = (float4*)(wts + (size_t)b * T_);
#pragma unroll
    for (int i = 0; i < T_ / 4 / 256; ++i) {
        float4 v = wp[tid + i * 256];
        v.x *= invZ; v.y *= invZ; v.z *= invZ; v.w *= invZ;
        wp[tid + i * 256] = v;
    }
}

extern "C" void kernel_launch(void* const* d_in, const int* in_sizes, int n_in,
                              void* d_out, int out_size, void* d_ws, size_t ws_size,
                              hipStream_t stream) {
    const float* x    = (const float*)d_in[0];   // [B,T,D]
    const float* W    = (const float*)d_in[1];   // [D,U]
    const float* bias = (const float*)d_in[2];   // [U]
    const float* uvec = (const float*)d_in[3];   // [U,1]

    float* out = (float*)d_out;
    float* ctx = out;            // context: B*D floats
    float* wts = out + B_ * D_;  // attention weights: B*T floats (e between kernels)

    unsigned short* whi = (unsigned short*)d_ws;     // 32 KB
    unsigned short* wlo = whi + D_ * U_;             // 32 KB
    float* Zp = (float*)(wlo + D_ * U_);             // 512 partial Z
    float* Pp = Zp + B_ * BPB;                       // 512 x 256 partial context

    wprep_kernel<<<D_ * U_ / 256, 256, 0, stream>>>(W, whi, wlo);
    fused_main<<<B_ * BPB, 256, 0, stream>>>(x, whi, wlo, bias, uvec, wts, Zp, Pp);
    finalize_kernel<<<B_, 256, 0, stream>>>(wts, Zp, Pp, ctx);
}

// Round 8
// 410.974 us; speedup vs baseline: 1.6478x; 1.1058x over previous
//
#include <hip/hip_runtime.h>
#include <math.h>

#define B_ 64
#define T_ 4096
#define D_ 256
#define U_ 64
#define RPB 64           // rows per block
#define NPB (T_ / RPB)   // blocks per batch = 64
#define NSTRIP (RPB / 16)
#define XPAD 264         // LDS x row stride (bf16 elems)

typedef float f32x4 __attribute__((ext_vector_type(4)));
typedef short bf16x8 __attribute__((ext_vector_type(8)));

__device__ __forceinline__ unsigned short f2bf_rne(float f) {
    unsigned u = __float_as_uint(f);
    unsigned r = u + 0x7fffu + ((u >> 16) & 1u);
    return (unsigned short)(r >> 16);
}
__device__ __forceinline__ float bfbits2f(unsigned short s) {
    return __uint_as_float(((unsigned)s) << 16);
}

// Pack W [D,U] fp32 into MFMA B-fragment order, split hi/lo bf16.
// Fragment (ks,nt,lane,j): value = W[k = ks*32 + (lane>>4)*8 + j][n = nt*16 + (lane&15)]
__global__ __launch_bounds__(256) void wprep_kernel(
    const float* __restrict__ W, unsigned short* __restrict__ whi,
    unsigned short* __restrict__ wlo)
{
    int fi = blockIdx.x * 256 + threadIdx.x;   // 0..16383, grid=64
    int j    = fi & 7;
    int lane = (fi >> 3) & 63;
    int tile = fi >> 9;            // 0..31
    int nt = tile & 3, ks = tile >> 2;
    int k = ks * 32 + (lane >> 4) * 8 + j;
    int n = nt * 16 + (lane & 15);
    float w = W[k * U_ + n];
    unsigned short hi = f2bf_rne(w);
    unsigned short lo = f2bf_rne(w - bfbits2f(hi));
    whi[fi] = hi;
    wlo[fi] = lo;
}

// Fused main. Grid = 4096 blocks, 4 waves each, 4 blocks/CU (16 waves/CU).
// Wave w holds B-fragments for column tile nt=w in 64 VGPRs (no W LDS).
// Strip loop (4 x 16 rows): A-frags direct from global (L1-shared across the
// 4 waves), split-bf16 MFMA into one acc; wave 0 stashes bf16-hi x in LDS.
// Epilogue per strip: tanh + u-dot + 16-lane reduce -> per-wave partials.
// Then: logits -> e -> wts/esh/Zp; context phase from LDS bf16-hi stash.
__global__ __launch_bounds__(256, 4) void fused_main(
    const float* __restrict__ x, const unsigned short* __restrict__ whi,
    const unsigned short* __restrict__ wlo, const float* __restrict__ bias,
    const float* __restrict__ uvec, float* __restrict__ wts,
    float* __restrict__ Zp, float* __restrict__ Pp)
{
    __shared__ unsigned short Xh[RPB * XPAD];  // 33 KB bf16-hi x stash
    __shared__ float part[RPB][4];             // per-wave logit partials, 1 KB
    __shared__ float esh[RPB];                 // 256 B

    int tid = threadIdx.x;
    int lane = tid & 63, wid = tid >> 6;
    int q = lane >> 4, r = lane & 15;

    // B-fragments for nt=wid, held in registers for the whole kernel.
    bf16x8 Bh[8], Bl[8];
    {
        const bf16x8* whiV = (const bf16x8*)whi;
        const bf16x8* wloV = (const bf16x8*)wlo;
#pragma unroll
        for (int ks = 0; ks < 8; ++ks) {
            Bh[ks] = whiV[(ks * 4 + wid) * 64 + lane];
            Bl[ks] = wloV[(ks * 4 + wid) * 64 + lane];
        }
    }

    int b = blockIdx.x / NPB;
    int pb = blockIdx.x % NPB;
    size_t row00 = (size_t)b * T_ + (size_t)pb * RPB;

    int col = wid * 16 + r;          // this wave's output column for this lane
    float bv = bias[col], uv = uvec[col];

    const float* xrow = x + (row00 + r) * D_ + q * 8;   // row r of strip, col grp q

#pragma unroll 1
    for (int s = 0; s < NSTRIP; ++s) {
        const float* xp = xrow + (size_t)s * 16 * D_;
        f32x4 acc = (f32x4){0.f, 0.f, 0.f, 0.f};

#pragma unroll
        for (int h = 0; h < 2; ++h) {
            // half-batch: 8 independent float4 loads (ks = h*4 .. h*4+3)
            float4 xb[8];
#pragma unroll
            for (int k2 = 0; k2 < 4; ++k2) {
                xb[2 * k2]     = *(const float4*)(xp + (h * 4 + k2) * 32);
                xb[2 * k2 + 1] = *(const float4*)(xp + (h * 4 + k2) * 32 + 4);
            }
#pragma unroll
            for (int k2 = 0; k2 < 4; ++k2) {
                int ks = h * 4 + k2;
                float4 va = xb[2 * k2], vb = xb[2 * k2 + 1];
                float f[8] = {va.x, va.y, va.z, va.w, vb.x, vb.y, vb.z, vb.w};
                union { bf16x8 v; unsigned short sh[8]; uint4 u; } hi_, lo_;
#pragma unroll
                for (int j = 0; j < 8; ++j) {
                    unsigned short a = f2bf_rne(f[j]);
                    hi_.sh[j] = a;
                    lo_.sh[j] = f2bf_rne(f[j] - bfbits2f(a));
                }
                if (wid == 0)   // one wave stashes the bf16-hi x tile
                    *(uint4*)(&Xh[(s * 16 + r) * XPAD + ks * 32 + q * 8]) = hi_.u;
                acc = __builtin_amdgcn_mfma_f32_16x16x32_bf16(hi_.v, Bh[ks], acc, 0, 0, 0);
                acc = __builtin_amdgcn_mfma_f32_16x16x32_bf16(hi_.v, Bl[ks], acc, 0, 0, 0);
                acc = __builtin_amdgcn_mfma_f32_16x16x32_bf16(lo_.v, Bh[ks], acc, 0, 0, 0);
            }
        }

        // Epilogue: acc[i] = (row q*4+i, col). score=tanh(acc+bias), *u, then
        // sum over the 16 cols of this wave's tile (r-lanes).
        float p0 = fmaf(1.f - 2.f / (__expf(2.f * (acc[0] + bv)) + 1.f), uv, 0.f);
        float p1 = fmaf(1.f - 2.f / (__expf(2.f * (acc[1] + bv)) + 1.f), uv, 0.f);
        float p2 = fmaf(1.f - 2.f / (__expf(2.f * (acc[2] + bv)) + 1.f), uv, 0.f);
        float p3 = fmaf(1.f - 2.f / (__expf(2.f * (acc[3] + bv)) + 1.f), uv, 0.f);
#pragma unroll
        for (int off = 1; off < 16; off <<= 1) {
            p0 += __shfl_xor(p0, off, 64);
            p1 += __shfl_xor(p1, off, 64);
            p2 += __shfl_xor(p2, off, 64);
            p3 += __shfl_xor(p3, off, 64);
        }
        if (r == 0) {
            int row = s * 16 + q * 4;
            part[row + 0][wid] = p0;
            part[row + 1][wid] = p1;
            part[row + 2][wid] = p2;
            part[row + 3][wid] = p3;
        }
    }
    __syncthreads();

    // logits -> e (wave 0 covers the 64 rows); Zp[block] = sum e.
    if (wid == 0) {
        float lg = (part[lane][0] + part[lane][1]) + (part[lane][2] + part[lane][3]);
        float e = __expf(lg);
        esh[lane] = e;
        wts[row00 + lane] = e;
        float z = e;
#pragma unroll
        for (int off = 1; off < 64; off <<= 1) z += __shfl_xor(z, off, 64);
        if (lane == 0) Zp[blockIdx.x] = z;
    }
    __syncthreads();

    // Context phase: P[col] = sum_rows e[row]*xhi[row][col] from LDS.
    int colg = tid & 31, ph = tid >> 5;     // 8 cols per thread, 8 row-phases
    float pacc[8];
#pragma unroll
    for (int j = 0; j < 8; ++j) pacc[j] = 0.f;
#pragma unroll 2
    for (int i = 0; i < RPB; i += 8) {
        int row = i + ph;
        float w = esh[row];
        union { uint4 u; unsigned short sh[8]; } v;
        v.u = *(const uint4*)(&Xh[row * XPAD + colg * 8]);
#pragma unroll
        for (int j = 0; j < 8; ++j)
            pacc[j] = fmaf(w, bfbits2f(v.sh[j]), pacc[j]);
    }
    __syncthreads();                        // done reading Xh; reuse as reduce buf
    float* red = (float*)Xh;                // 8*256 floats = 8 KB, fits in Xh
#pragma unroll
    for (int j = 0; j < 8; ++j) red[ph * 256 + colg * 8 + j] = pacc[j];
    __syncthreads();
    float ssum = 0.f;
#pragma unroll
    for (int p = 0; p < 8; ++p) ssum += red[p * 256 + tid];
    Pp[(size_t)blockIdx.x * D_ + tid] = ssum;
}

// Finalize: Z_b = sum of NPB partials; ctx = sum(Pp)/Z; wts *= 1/Z.
__global__ __launch_bounds__(256) void finalize_kernel(
    float* __restrict__ wts, const float* __restrict__ Zp,
    const float* __restrict__ Pp, float* __restrict__ ctx)
{
    int b = blockIdx.x;
    int tid = threadIdx.x;
    float Z = 0.f;
#pragma unroll 8
    for (int i = 0; i < NPB; ++i) Z += Zp[b * NPB + i];   // uniform s_loads
    float invZ = 1.f / Z;

    float s = 0.f;
#pragma unroll 4
    for (int i = 0; i < NPB; ++i) s += Pp[(size_t)(b * NPB + i) * D_ + tid];
    ctx[b * D_ + tid] = s * invZ;

    float4* wp = (float4*)(wts + (size_t)b * T_);
#pragma unroll
    for (int i = 0; i < T_ / 4 / 256; ++i) {
        float4 v = wp[tid + i * 256];
        v.x *= invZ; v.y *= invZ; v.z *= invZ; v.w *= invZ;
        wp[tid + i * 256] = v;
    }
}

extern "C" void kernel_launch(void* const* d_in, const int* in_sizes, int n_in,
                              void* d_out, int out_size, void* d_ws, size_t ws_size,
                              hipStream_t stream) {
    const float* x    = (const float*)d_in[0];   // [B,T,D]
    const float* W    = (const float*)d_in[1];   // [D,U]
    const float* bias = (const float*)d_in[2];   // [U]
    const float* uvec = (const float*)d_in[3];   // [U,1]

    float* out = (float*)d_out;
    float* ctx = out;            // context: B*D floats
    float* wts = out + B_ * D_;  // attention weights: B*T floats (e between kernels)

    unsigned short* whi = (unsigned short*)d_ws;     // 32 KB
    unsigned short* wlo = whi + D_ * U_;             // 32 KB
    float* Zp = (float*)(wlo + D_ * U_);             // 4096 partial Z
    float* Pp = Zp + B_ * NPB;                       // 4096 x 256 partial context

    wprep_kernel<<<D_ * U_ / 256, 256, 0, stream>>>(W, whi, wlo);
    fused_main<<<(B_ * T_) / RPB, 256, 0, stream>>>(x, whi, wlo, bias, uvec, wts, Zp, Pp);
    finalize_kernel<<<B_, 256, 0, stream>>>(wts, Zp, Pp, ctx);
}

// Round 9
// 370.917 us; speedup vs baseline: 1.8258x; 1.1080x over previous
//
#include <hip/hip_runtime.h>
#include <math.h>

#define B_ 64
#define T_ 4096
#define D_ 256
#define U_ 64
#define RPB 32           // rows per block (2 strips of 16)
#define NPB (T_ / RPB)   // blocks per batch = 128
#define XPAD 264         // LDS x row stride (bf16 elems), pad vs 256

typedef float f32x4 __attribute__((ext_vector_type(4)));
typedef short bf16x8 __attribute__((ext_vector_type(8)));

__device__ __forceinline__ unsigned short f2bf_rne(float f) {
    unsigned u = __float_as_uint(f);
    unsigned r = u + 0x7fffu + ((u >> 16) & 1u);
    return (unsigned short)(r >> 16);
}
__device__ __forceinline__ float bfbits2f(unsigned short s) {
    return __uint_as_float(((unsigned)s) << 16);
}

// Pack W [D,U] fp32 into MFMA B-fragment order, split hi/lo bf16.
// Fragment (ks,nt,lane,j): value = W[k = ks*32 + (lane>>4)*8 + j][n = nt*16 + (lane&15)]
__global__ __launch_bounds__(256) void wprep_kernel(
    const float* __restrict__ W, unsigned short* __restrict__ whi,
    unsigned short* __restrict__ wlo)
{
    int fi = blockIdx.x * 256 + threadIdx.x;   // 0..16383, grid=64
    int j    = fi & 7;
    int lane = (fi >> 3) & 63;
    int tile = fi >> 9;            // 0..31
    int nt = tile & 3, ks = tile >> 2;
    int k = ks * 32 + (lane >> 4) * 8 + j;
    int n = nt * 16 + (lane & 15);
    float w = W[k * U_ + n];
    unsigned short hi = f2bf_rne(w);
    unsigned short lo = f2bf_rne(w - bfbits2f(hi));
    whi[fi] = hi;
    wlo[fi] = lo;
}

// Fused main. Grid = 8192 blocks (32 rows each), 4 blocks/CU (16 waves/CU).
// Stage: x -> bf16 hi/lo converted ONCE cooperatively -> LDS (34 KB).
// MFMA: wave w = column tile nt=w; B-frags in 64 VGPRs (loaded once);
// A-frags via ds_read_b128. Epilogue -> per-wave logit partials -> e, Zp.
// Context phase: P[d] = sum_rows e*xhi from LDS; per-block partials -> Pp.
__global__ __launch_bounds__(256, 4) void fused_main(
    const float* __restrict__ x, const unsigned short* __restrict__ whi,
    const unsigned short* __restrict__ wlo, const float* __restrict__ bias,
    const float* __restrict__ uvec, float* __restrict__ wts,
    float* __restrict__ Zp, float* __restrict__ Pp)
{
    __shared__ unsigned short Ahi[RPB * XPAD];   // 16.9 KB
    __shared__ unsigned short Alo[RPB * XPAD];   // 16.9 KB
    __shared__ float part[RPB][4];               // 512 B
    __shared__ float esh[RPB];                   // 128 B

    int tid = threadIdx.x;
    int lane = tid & 63, wid = tid >> 6;
    int q = lane >> 4, r = lane & 15;

    // B-fragments for this wave's column tile (nt = wid), resident all kernel.
    bf16x8 Bh[8], Bl[8];
    {
        const bf16x8* whiV = (const bf16x8*)whi;
        const bf16x8* wloV = (const bf16x8*)wlo;
#pragma unroll
        for (int ks = 0; ks < 8; ++ks) {
            Bh[ks] = whiV[(ks * 4 + wid) * 64 + lane];
            Bl[ks] = wloV[(ks * 4 + wid) * 64 + lane];
        }
    }

    int b = blockIdx.x / NPB;
    int pb = blockIdx.x % NPB;
    size_t row00 = (size_t)b * T_ + (size_t)pb * RPB;

    // ---- cooperative stage: 2048 float4 = 32 rows x 256 cols, convert once ----
    {
        const float4* xs4 = (const float4*)(x + row00 * D_);
        float4 xs[8];
#pragma unroll
        for (int i = 0; i < 8; ++i) xs[i] = xs4[tid + i * 256];
#pragma unroll
        for (int i = 0; i < 8; ++i) {
            int f = tid + i * 256;
            int row = f >> 6, c4 = f & 63;
            float4 v = xs[i];
            unsigned short h0 = f2bf_rne(v.x), h1 = f2bf_rne(v.y),
                           h2 = f2bf_rne(v.z), h3 = f2bf_rne(v.w);
            unsigned short l0 = f2bf_rne(v.x - bfbits2f(h0)),
                           l1 = f2bf_rne(v.y - bfbits2f(h1)),
                           l2 = f2bf_rne(v.z - bfbits2f(h2)),
                           l3 = f2bf_rne(v.w - bfbits2f(h3));
            int base = row * XPAD + c4 * 4;
            uint2 hp = { (unsigned)h0 | ((unsigned)h1 << 16),
                         (unsigned)h2 | ((unsigned)h3 << 16) };
            uint2 lp = { (unsigned)l0 | ((unsigned)l1 << 16),
                         (unsigned)l2 | ((unsigned)l3 << 16) };
            *(uint2*)(&Ahi[base]) = hp;
            *(uint2*)(&Alo[base]) = lp;
        }
    }
    __syncthreads();

    // ---- MFMA: 2 strips of 16 rows ----
    int col = wid * 16 + r;
    float bv = bias[col], uv = uvec[col];

#pragma unroll
    for (int s = 0; s < 2; ++s) {
        f32x4 acc = (f32x4){0.f, 0.f, 0.f, 0.f};
        int arow = (s * 16 + r) * XPAD + q * 8;
#pragma unroll
        for (int ks = 0; ks < 8; ++ks) {
            bf16x8 ahi = *(const bf16x8*)(&Ahi[arow + ks * 32]);
            bf16x8 alo = *(const bf16x8*)(&Alo[arow + ks * 32]);
            acc = __builtin_amdgcn_mfma_f32_16x16x32_bf16(ahi, Bh[ks], acc, 0, 0, 0);
            acc = __builtin_amdgcn_mfma_f32_16x16x32_bf16(ahi, Bl[ks], acc, 0, 0, 0);
            acc = __builtin_amdgcn_mfma_f32_16x16x32_bf16(alo, Bh[ks], acc, 0, 0, 0);
        }
        // score = tanh(acc+bias); p = score*u; reduce over this wave's 16 cols.
        float p0 = fmaf(1.f - 2.f / (__expf(2.f * (acc[0] + bv)) + 1.f), uv, 0.f);
        float p1 = fmaf(1.f - 2.f / (__expf(2.f * (acc[1] + bv)) + 1.f), uv, 0.f);
        float p2 = fmaf(1.f - 2.f / (__expf(2.f * (acc[2] + bv)) + 1.f), uv, 0.f);
        float p3 = fmaf(1.f - 2.f / (__expf(2.f * (acc[3] + bv)) + 1.f), uv, 0.f);
#pragma unroll
        for (int off = 1; off < 16; off <<= 1) {
            p0 += __shfl_xor(p0, off, 64);
            p1 += __shfl_xor(p1, off, 64);
            p2 += __shfl_xor(p2, off, 64);
            p3 += __shfl_xor(p3, off, 64);
        }
        if (r == 0) {
            int row = s * 16 + q * 4;
            part[row + 0][wid] = p0;
            part[row + 1][wid] = p1;
            part[row + 2][wid] = p2;
            part[row + 3][wid] = p3;
        }
    }
    __syncthreads();

    // ---- logits -> e -> esh/wts; Zp[block] ----
    if (wid == 0 && lane < RPB) {
        float lg = (part[lane][0] + part[lane][1]) + (part[lane][2] + part[lane][3]);
        float e = __expf(lg);
        esh[lane] = e;
        wts[row00 + lane] = e;
        float z = e;
#pragma unroll
        for (int off = 1; off < 32; off <<= 1) z += __shfl_xor(z, off, 32);
        if (lane == 0) Zp[blockIdx.x] = z;
    }
    __syncthreads();

    // ---- context: P[col] = sum_rows e[row]*xhi[row][col] from LDS ----
    int colg = tid & 31, ph = tid >> 5;     // 8 cols/thread, 8 row-phases
    float pacc[8];
#pragma unroll
    for (int j = 0; j < 8; ++j) pacc[j] = 0.f;
#pragma unroll
    for (int i = 0; i < RPB; i += 8) {
        int row = i + ph;
        float w = esh[row];
        union { uint4 u; unsigned short sh[8]; } v;
        v.u = *(const uint4*)(&Ahi[row * XPAD + colg * 8]);
#pragma unroll
        for (int j = 0; j < 8; ++j)
            pacc[j] = fmaf(w, bfbits2f(v.sh[j]), pacc[j]);
    }
    __syncthreads();                 // Alo no longer needed; reuse as reduce buf
    float* red = (float*)Alo;        // 8 KB
#pragma unroll
    for (int j = 0; j < 8; ++j) red[ph * 256 + colg * 8 + j] = pacc[j];
    __syncthreads();
    float ssum = 0.f;
#pragma unroll
    for (int p = 0; p < 8; ++p) ssum += red[p * 256 + tid];
    Pp[(size_t)blockIdx.x * D_ + tid] = ssum;
}

// Finalize: Z_b = sum of NPB partials; ctx = sum(Pp)/Z; wts *= 1/Z.
__global__ __launch_bounds__(256) void finalize_kernel(
    float* __restrict__ wts, const float* __restrict__ Zp,
    const float* __restrict__ Pp, float* __restrict__ ctx)
{
    int b = blockIdx.x;
    int tid = threadIdx.x;
    float Z = 0.f;
#pragma unroll 8
    for (int i = 0; i < NPB; ++i) Z += Zp[b * NPB + i];   // uniform s_loads
    float invZ = 1.f / Z;

    float s = 0.f;
#pragma unroll 4
    for (int i = 0; i < NPB; ++i) s += Pp[(size_t)(b * NPB + i) * D_ + tid];
    ctx[b * D_ + tid] = s * invZ;

    float4* wp = (float4*)(wts + (size_t)b * T_);
#pragma unroll
    for (int i = 0; i < T_ / 4 / 256; ++i) {
        float4 v = wp[tid + i * 256];
        v.x *= invZ; v.y *= invZ; v.z *= invZ; v.w *= invZ;
        wp[tid + i * 256] = v;
    }
}

extern "C" void kernel_launch(void* const* d_in, const int* in_sizes, int n_in,
                              void* d_out, int out_size, void* d_ws, size_t ws_size,
                              hipStream_t stream) {
    const float* x    = (const float*)d_in[0];   // [B,T,D]
    const float* W    = (const float*)d_in[1];   // [D,U]
    const float* bias = (const float*)d_in[2];   // [U]
    const float* uvec = (const float*)d_in[3];   // [U,1]

    float* out = (float*)d_out;
    float* ctx = out;            // context: B*D floats
    float* wts = out + B_ * D_;  // attention weights: B*T floats (e between kernels)

    unsigned short* whi = (unsigned short*)d_ws;     // 32 KB
    unsigned short* wlo = whi + D_ * U_;             // 32 KB
    float* Zp = (float*)(wlo + D_ * U_);             // 8192 partial Z
    float* Pp = Zp + B_ * NPB;                       // 8192 x 256 partial context

    wprep_kernel<<<D_ * U_ / 256, 256, 0, stream>>>(W, whi, wlo);
    fused_main<<<(B_ * T_) / RPB, 256, 0, stream>>>(x, whi, wlo, bias, uvec, wts, Zp, Pp);
    finalize_kernel<<<B_, 256, 0, stream>>>(wts, Zp, Pp, ctx);
}